// Round 10
// baseline (252.278 us; speedup 1.0000x reference)
//
#include <hip/hip_runtime.h>
#include <math.h>

typedef _Float16 f16;
typedef _Float16 f16x8 __attribute__((ext_vector_type(8)));
typedef _Float16 f16x4 __attribute__((ext_vector_type(4)));
typedef float    f32x4 __attribute__((ext_vector_type(4)));

#define BATCH 32
#define TT    600
#define CC    64
#define SEG   50
#define HH    512
#define G4    2048
#define FF    2144   // IN_SIZE = 64 + 2080
#define MM    1600   // BATCH*SEG
#define MP    1664   // padded: 52*32 (s-major) = 26*64 M-tiles
#define NPAIR 2016   // C*(C-1)/2
#define CVB   512    // convert blocks appended to prep grid
#define WRK   208    // gemm worker blocks (each does 8 of the 1664 K-split pieces)
#define SLOT16 16384 // u16 elements per h slot (32*512)
#define BUFB  12288  // ring buffer stride: A 4K + B 8K

struct TV { int v[51]; };

// async global->LDS, 16B per lane. LDS dest must be wave-uniform base + lane*16.
__device__ __forceinline__ void async_copy16(char* lds, const char* g) {
  __builtin_amdgcn_global_load_lds(
      (const __attribute__((address_space(1))) unsigned int*)g,
      (__attribute__((address_space(3))) unsigned int*)lds, 16, 0, 0);
}

__device__ __forceinline__ float sigm(float x) { return 1.f / (1.f + __expf(-x)); }
__device__ __forceinline__ float tanh_(float x) {
  float ax = fabsf(x);
  float e  = __expf(2.f * ax);
  float t  = 1.f - 2.f / (e + 1.f);   // robust for large |x|
  return x < 0.f ? -t : t;
}
__device__ __forceinline__ unsigned short f16_bits(f16 v) {
  union { f16 f; unsigned short u; } c; c.f = v; return c.u;
}

// ---------------- kernel 1: feats (blocks 0..MP-1) + weight convert / gx bias-init ----
// Plain cached stores; dispatch boundary makes them visible to the fused kernel.
__global__ void prep_kernel(const float* __restrict__ x, f16* __restrict__ fhi, TV tv,
                            const float4* __restrict__ w_ih, const float4* __restrict__ w_hh,
                            f16x4* __restrict__ w16, f16x4* __restrict__ whh16,
                            unsigned int* __restrict__ ready,
                            const float* __restrict__ bih, const float* __restrict__ bhh,
                            float4* __restrict__ gx4) {
  __shared__ float xs[13 * CC];
  int m   = blockIdx.x;
  int tid = threadIdx.x;

  if (m >= MP) {              // ---- convert role ----
    int cb   = m - MP;
    int gtid = cb * 256 + tid;
    int nth  = CVB * 256;
    for (int i = gtid; i < G4 * FF / 4; i += nth) {
      float4 v = w_ih[i];
      f16x4 o = {(f16)v.x, (f16)v.y, (f16)v.z, (f16)v.w};
      w16[i] = o;
    }
    for (int i = gtid; i < G4 * HH / 4; i += nth) {
      float4 v = w_hh[i];
      f16x4 o = {(f16)v.x, (f16)v.y, (f16)v.z, (f16)v.w};
      whh16[i] = o;
    }
    // gx bias-init: workers ATOMIC-ADD their K-piece partial sums on top, so the
    // bias (bih+bhh) is pre-seeded here instead of added in the GEMM epilogue.
    for (int i = gtid; i < MP * (G4 / 4); i += nth) {
      int c4 = i & (G4 / 4 - 1);
      float4 bi = ((const float4*)bih)[c4];
      float4 bh = ((const float4*)bhh)[c4];
      float4 o = {bi.x + bh.x, bi.y + bh.y, bi.z + bh.z, bi.w + bh.w};
      gx4[i] = o;
    }
    if (cb == 0)               // zero 32 ready slots (512 u32) + 32 gx tile counters
      for (int i = tid; i < 544; i += 256) ready[i] = 0u;
    return;
  }

  f16* rhi = fhi + (size_t)m * FF;
  if (m >= MM) {              // zero-pad rows 1600..1663 (s = 50,51) for the GEMM M-edge
    unsigned int* a = (unsigned int*)rhi;
    for (int i = tid; i < FF / 2; i += 256) a[i] = 0u;
    return;
  }
  int bb = m & 31, ss = m >> 5;
  int t0 = tv.v[ss] - 1, t1 = tv.v[ss + 1] - 1;
  int len = t1 - t0;          // #intervals in segment (11..12)
  for (int i = tid; i < (len + 1) * CC; i += 256)
    xs[i] = x[(size_t)bb * TT * CC + (size_t)(t0 + (i >> 6)) * CC + (i & 63)];
  __syncthreads();

  if (tid < CC) {             // inc (cols 0..63) and xa (cols 2080..2143)
    float xa  = xs[tid];
    float inc = xs[len * CC + tid] - xa;
    rhi[tid] = (f16)inc;
    rhi[2080 + tid] = (f16)xa;
  }

  int p0 = tid * 8;           // 252 threads x 8 pairs = 2016 upper-tri pairs
  if (p0 < NPAIR) {
    int c = 0, rem = p0;
    while (rem >= 63 - c) { rem -= 63 - c; c++; }
    int d = c + 1 + rem;
    int cs[8], dd[8];
#pragma unroll
    for (int i = 0; i < 8; i++) {
      cs[i] = c; dd[i] = d;
      d++; if (d == 64) { c++; d = c + 1; }
    }
    float acc[8], xc[8], xd[8];
#pragma unroll
    for (int i = 0; i < 8; i++) { acc[i] = 0.f; xc[i] = xs[cs[i]]; xd[i] = xs[dd[i]]; }
    for (int t = 1; t <= len; t++) {
#pragma unroll
      for (int i = 0; i < 8; i++) {      // Levy area: sum x_c*dx_d - x_d*dx_c
        float nc = xs[t * CC + cs[i]], nd = xs[t * CC + dd[i]];
        acc[i] += xc[i] * (nd - xd[i]) - xd[i] * (nc - xc[i]);
        xc[i] = nc; xd[i] = nd;
      }
    }
#pragma unroll
    for (int i = 0; i < 8; i++) {
      int ci = cs[i], di = dd[i];
      float xac = xs[ci], xad = xs[di];
      float incc = xs[len * CC + ci] - xac, incd = xs[len * CC + di] - xad;
      float v = 0.5f * acc[i] - 0.5f * (xac * incd - xad * incc);
      rhi[64 + p0 + i] = (f16)v;
    }
  }
}

// ---------------- kernel 2: fused GEMM + LSTM, regular launch (240 blocks co-resident) ----
// Blocks 0..31: persistent LSTM — r3/7/9 proven coherence skeleton (sc1 h-stores +
//   block-barrier drain + flag; tid<32 flag poll + barrier). NEW this round: the
//   32KB DMA->LDS slot copy + drain + ds_reads are replaced by a 4-GROUP PIPELINED
//   DIRECT LOAD of the MFMA A-fragments into VGPRs (2 groups in flight, counted
//   vmcnt(8), sched_barrier pins order). Same addresses/values as the verified LDS
//   path — removes one full barrier + the copy round trip from the serial chain.
//   (r2's failure was loading all 64 frags at once -> regalloc bail; 4-group keeps
//   only 16 f16x8 live.)
// Blocks 32..239: GEMM workers, 4-way K-split (validated r9), atomic-add epilogue
//   into bias-seeded gx (validated r7), ring-5 counted-vmcnt pipeline (r3) +
//   both-sides LDS swizzle (r5: conflicts 2.78M -> 102K). Counter target 64.
__global__ __launch_bounds__(256) void fused_kernel(
    const f16* __restrict__ fhi, const f16* __restrict__ w16,
    const float* __restrict__ bih, const float* __restrict__ bhh,
    const f16* __restrict__ whh16, float* __restrict__ gx,
    unsigned short* __restrict__ hbuf, unsigned int* __restrict__ ready,
    unsigned int* __restrict__ gxcnt, float* __restrict__ out) {
  __shared__ __align__(16) char smem[61440];  // gemm: 5 x 12KB ring ; lstm: gb at +32768
  int tid  = threadIdx.x;
  int lane = tid & 63;

  if (blockIdx.x >= 32) {
    // ================= GEMM worker role =================
    int w  = blockIdx.x - 32;
    int wn = tid >> 6;
    int rowq = tid >> 2;            // 0..63 (LDS row this thread stages)
    int ldst = tid * 16;            // linear LDS dest (global_load_lds requirement)
    int quad = lane >> 4;           // 0..3 read quad
    int am   = lane & 15;

    // both-sides swizzle: LDS slot (row, q) holds global quad q ^ ((row>>1)&3).
    int qsrc = ((tid & 3) ^ ((tid >> 3) & 3)) * 8;   // f16 elements within 32-col slice

    // precomputed swizzled read offsets (within one 12KB ring buffer)
    int offA[4], offB[2];
#pragma unroll
    for (int mi = 0; mi < 4; mi++) {
      int ra = mi * 16 + am;
      offA[mi] = ra * 64 + ((quad ^ ((ra >> 1) & 3)) * 16);
    }
#pragma unroll
    for (int ni = 0; ni < 2; ni++) {
      int rb = wn * 32 + ni * 16 + am;   // 0..127 spans B0 (pb0) then B1 (pb1)
      offB[ni] = 4096 + rb * 64 + ((quad ^ ((rb >> 1) & 3)) * 16);
    }

    for (int t = 0; t < 8; t++) {
      int id  = w + t * WRK;        // 0..1663
      int nt  = id & 15;
      int mtk = id >> 4;            // 0..103 (mt-major, kh inner)
      int kh  = mtk & 3;
      int mt  = mtk >> 2;           // 0..25
      int m0 = mt * 64, n0 = nt * 128;
      int kbase = kh * 544;         // f16 elements (17 iters x 32); kh3: 16 iters
      int KTh  = (kh == 3) ? 16 : 17;

      const f16* pa  = fhi + (size_t)(m0 + rowq) * FF + kbase + qsrc;
      const f16* pb0 = w16 + (size_t)(n0 + rowq) * FF + kbase + qsrc;
      const f16* pb1 = pb0 + (size_t)64 * FF;

      f32x4 zero4 = {0.f, 0.f, 0.f, 0.f};
      f32x4 acc[4][2];
#pragma unroll
      for (int i = 0; i < 4; i++) { acc[i][0] = zero4; acc[i][1] = zero4; }

      // prologue: stage kt = 0..2 into ring slots 0..2 (9 copies in flight)
      for (int kp = 0; kp < 3; kp++) {
        char* b = smem + kp * BUFB;
        int koff = kp * 32;
        async_copy16(b + ldst,        (const char*)(pa + koff));
        async_copy16(b + 4096 + ldst, (const char*)(pb0 + koff));
        async_copy16(b + 8192 + ldst, (const char*)(pb1 + koff));
      }

      for (int kt = 0; kt < KTh; kt++) {
        // prefetch kt+3 into ring slot (kt+3)%5; that slot was last READ at iter
        // kt-2 (completed before barrier kt-1) -> WAR is barrier-separated.
        if (kt + 3 < KTh) {
          char* b = smem + ((kt + 3) % 5) * BUFB;
          int koff = (kt + 3) * 32;
          async_copy16(b + ldst,        (const char*)(pa + koff));
          async_copy16(b + 4096 + ldst, (const char*)(pb0 + koff));
          async_copy16(b + 8192 + ldst, (const char*)(pb1 + koff));
          asm volatile("s_waitcnt vmcnt(9)" ::: "memory");   // kt's 3 copies done
        } else if (kt + 3 == KTh) {
          asm volatile("s_waitcnt vmcnt(6)" ::: "memory");
        } else if (kt + 2 == KTh) {
          asm volatile("s_waitcnt vmcnt(3)" ::: "memory");
        } else {
          asm volatile("s_waitcnt vmcnt(0)" ::: "memory");
        }
        __builtin_amdgcn_s_barrier();       // all waves' kt-copies complete
        __builtin_amdgcn_sched_barrier(0);  // no ds_read hoist above the barrier

        char* bb = smem + (kt % 5) * BUFB;
        f16x8 bfr[2];
        bfr[0] = *(const f16x8*)(bb + offB[0]);
        bfr[1] = *(const f16x8*)(bb + offB[1]);
#pragma unroll
        for (int mi = 0; mi < 4; mi++) {
          f16x8 ah = *(const f16x8*)(bb + offA[mi]);
#pragma unroll
          for (int ni = 0; ni < 2; ni++)
            acc[mi][ni] = __builtin_amdgcn_mfma_f32_16x16x32_f16(ah, bfr[ni], acc[mi][ni], 0, 0, 0);
        }
      }

      // epilogue: f32 atomic-add partial sums into bias-seeded gx. Atomics act at
      // L3 (device coherence point); __syncthreads drains vmcnt(0) so all adds are
      // globally visible before the tile counter increments.
#pragma unroll
      for (int ni = 0; ni < 2; ni++) {
        int ncol = n0 + wn * 32 + ni * 16 + am;
#pragma unroll
        for (int mi = 0; mi < 4; mi++) {
          int mrow = m0 + mi * 16 + quad * 4;
#pragma unroll
          for (int r = 0; r < 4; r++)
            __hip_atomic_fetch_add(&gx[(size_t)(mrow + r) * G4 + ncol],
                                   acc[mi][ni][r],
                                   __ATOMIC_RELAXED, __HIP_MEMORY_SCOPE_AGENT);
        }
      }
      __syncthreads();   // drains vmcnt(0): all this block's gx adds acked
      if (tid == 0)
        __hip_atomic_fetch_add(&gxcnt[mt], 1u, __ATOMIC_RELAXED,
                               __HIP_MEMORY_SCOPE_AGENT);
    }
    return;
  }

  // ================= LSTM role (blocks 0..31) =================
  float* gb = (float*)(smem + 32768);           // 8 KB gate exchange [gate][b][16]

  int gate = tid >> 6;
  int u0   = blockIdx.x * 16;
  int wg   = blockIdx.x;

  // preload w_hh fragments: B[k][n] = w_hh[n][k], n = gate*512 + u0 + (lane&15)
  f16x8 bf[16];
  {
    const f16* wrow = whh16 + (size_t)(gate * HH + u0 + (lane & 15)) * HH + (lane >> 4) * 8;
#pragma unroll
    for (int ks = 0; ks < 16; ks++) bf[ks] = *(const f16x8*)(wrow + ks * 32);
  }

  int b1 = tid >> 4;
  int ul = tid & 15;
  float cst0 = 0.f, cst1 = 0.f;
  int aq  = (lane >> 4);
  int am  = (lane & 15);
  int col = lane & 15;
  int rbase = (lane >> 4) * 4;

  for (int s = 0; s < SEG; s++) {
    // gate on gx M-tile (s>>1); odd s was confirmed at s-1. The __syncthreads after
    // the poll orders the subsequent plain gx loads (no hoist past a barrier).
    if ((s & 1) == 0) {
      if (tid == 0) {
        while (__hip_atomic_load(&gxcnt[s >> 1], __ATOMIC_RELAXED,
                                 __HIP_MEMORY_SCOPE_AGENT) < 64u)
          __builtin_amdgcn_s_sleep(1);
      }
      __syncthreads();
    }

    // gx prefetch (plain cached loads; post-gate first touch -> fresh from L3)
    float gxr0[4], gxr1[4];
#pragma unroll
    for (int r = 0; r < 4; r++) {
      int b = rbase + r;
      gxr0[r] = gx[(size_t)((s << 5) + b) * G4 + gate * HH + u0 + col];
      gxr1[r] = gx[(size_t)((s << 5) + b + 16) * G4 + gate * HH + u0 + col];
    }

    f32x4 acc0 = {0.f, 0.f, 0.f, 0.f};
    f32x4 acc1 = {0.f, 0.f, 0.f, 0.f};

    if (s > 0) {
      // wait: all 32 WGs published h[s]. The barrier's implicit vmcnt(0) drain
      // also empties the VMEM queue -> the counted vmcnt(N) below are exact.
      unsigned int tgt = (unsigned int)s;
      if (tid < 32) {
        while (__hip_atomic_load(&ready[tid * 16], __ATOMIC_RELAXED,
                                 __HIP_MEMORY_SCOPE_AGENT) < tgt)
          __builtin_amdgcn_s_sleep(1);
      }
      __syncthreads();

      // pipelined direct fragment loads (addresses identical to the verified LDS
      // path: lane (aq,am) reads slot + ((ks*4+aq)*32+am)*16 B, +256B for b>=16).
      // 4 groups x 4 ks x 2 frags; 2 groups (16 x 16B loads) in flight.
      const char* hrd = (const char*)(hbuf + (size_t)s * SLOT16)
                      + (size_t)((aq * 32 + am) * 16);
      f16x8 pa0[4], pa1[4], qa0[4], qa1[4];
#pragma unroll
      for (int j = 0; j < 4; j++) {            // group 0: ks 0..3
        pa0[j] = *(const f16x8*)(hrd + j * 2048);
        pa1[j] = *(const f16x8*)(hrd + j * 2048 + 256);
      }
#pragma unroll
      for (int j = 0; j < 4; j++) {            // group 1: ks 4..7
        qa0[j] = *(const f16x8*)(hrd + (4 + j) * 2048);
        qa1[j] = *(const f16x8*)(hrd + (4 + j) * 2048 + 256);
      }
      asm volatile("s_waitcnt vmcnt(8)" ::: "memory");   // group 0 landed
      __builtin_amdgcn_sched_barrier(0);
#pragma unroll
      for (int j = 0; j < 4; j++) {
        acc0 = __builtin_amdgcn_mfma_f32_16x16x32_f16(pa0[j], bf[j], acc0, 0, 0, 0);
        acc1 = __builtin_amdgcn_mfma_f32_16x16x32_f16(pa1[j], bf[j], acc1, 0, 0, 0);
      }
      __builtin_amdgcn_sched_barrier(0);
#pragma unroll
      for (int j = 0; j < 4; j++) {            // group 2 reuses p-regs: ks 8..11
        pa0[j] = *(const f16x8*)(hrd + (8 + j) * 2048);
        pa1[j] = *(const f16x8*)(hrd + (8 + j) * 2048 + 256);
      }
      asm volatile("s_waitcnt vmcnt(8)" ::: "memory");   // group 1 landed
      __builtin_amdgcn_sched_barrier(0);
#pragma unroll
      for (int j = 0; j < 4; j++) {
        acc0 = __builtin_amdgcn_mfma_f32_16x16x32_f16(qa0[j], bf[4 + j], acc0, 0, 0, 0);
        acc1 = __builtin_amdgcn_mfma_f32_16x16x32_f16(qa1[j], bf[4 + j], acc1, 0, 0, 0);
      }
      __builtin_amdgcn_sched_barrier(0);
#pragma unroll
      for (int j = 0; j < 4; j++) {            // group 3 reuses q-regs: ks 12..15
        qa0[j] = *(const f16x8*)(hrd + (12 + j) * 2048);
        qa1[j] = *(const f16x8*)(hrd + (12 + j) * 2048 + 256);
      }
      asm volatile("s_waitcnt vmcnt(8)" ::: "memory");   // group 2 landed
      __builtin_amdgcn_sched_barrier(0);
#pragma unroll
      for (int j = 0; j < 4; j++) {
        acc0 = __builtin_amdgcn_mfma_f32_16x16x32_f16(pa0[j], bf[8 + j], acc0, 0, 0, 0);
        acc1 = __builtin_amdgcn_mfma_f32_16x16x32_f16(pa1[j], bf[8 + j], acc1, 0, 0, 0);
      }
      asm volatile("s_waitcnt vmcnt(0)" ::: "memory");   // group 3 landed
      __builtin_amdgcn_sched_barrier(0);
#pragma unroll
      for (int j = 0; j < 4; j++) {
        acc0 = __builtin_amdgcn_mfma_f32_16x16x32_f16(qa0[j], bf[12 + j], acc0, 0, 0, 0);
        acc1 = __builtin_amdgcn_mfma_f32_16x16x32_f16(qa1[j], bf[12 + j], acc1, 0, 0, 0);
      }
    }

#pragma unroll
    for (int r = 0; r < 4; r++) {
      int b = rbase + r;
      gb[(gate * 32 + b) * 16 + col]      = acc0[r] + gxr0[r];
      gb[(gate * 32 + b + 16) * 16 + col] = acc1[r] + gxr1[r];
    }
    __syncthreads();

    unsigned short* hwr = hbuf + (size_t)(s + 1) * SLOT16;
    int k = u0 + ul;
    float h0, h1;
    {
      float i_ = sigm(gb[(0 * 32 + b1) * 16 + ul]), f_ = sigm(gb[(1 * 32 + b1) * 16 + ul]);
      float g_ = tanh_(gb[(2 * 32 + b1) * 16 + ul]), o_ = sigm(gb[(3 * 32 + b1) * 16 + ul]);
      cst0 = f_ * cst0 + i_ * g_;
      h0 = o_ * tanh_(cst0);
    }
    {
      int b2 = b1 + 16;
      float i_ = sigm(gb[(0 * 32 + b2) * 16 + ul]), f_ = sigm(gb[(1 * 32 + b2) * 16 + ul]);
      float g_ = tanh_(gb[(2 * 32 + b2) * 16 + ul]), o_ = sigm(gb[(3 * 32 + b2) * 16 + ul]);
      cst1 = f_ * cst1 + i_ * g_;
      h1 = o_ * tanh_(cst1);
    }

    if (s < SEG - 1) {
      // publish h[s+1] into slot s+1 (sc1, write-through); __syncthreads drains
      // vmcnt(0) so stores are at the coherence point before the flag goes out
      __hip_atomic_store(hwr + ((k >> 3) * 32 + b1) * 8 + (k & 7),
                         f16_bits((f16)h0), __ATOMIC_RELAXED, __HIP_MEMORY_SCOPE_AGENT);
      __hip_atomic_store(hwr + ((k >> 3) * 32 + (b1 + 16)) * 8 + (k & 7),
                         f16_bits((f16)h1), __ATOMIC_RELAXED, __HIP_MEMORY_SCOPE_AGENT);
      __syncthreads();
      if (tid == 0)
        __hip_atomic_store(&ready[wg * 16], (unsigned int)(s + 1),
                           __ATOMIC_RELAXED, __HIP_MEMORY_SCOPE_AGENT);
    }

    // out stores AFTER the flag publish: their HBM ack is off the critical chain
    out[(size_t)(b1 * SEG + s) * HH + k] = h0;
    out[(size_t)((b1 + 16) * SEG + s) * HH + k] = h1;
  }
}

// ---------------- launch ----------------
extern "C" void kernel_launch(void* const* d_in, const int* in_sizes, int n_in,
                              void* d_out, int out_size, void* d_ws, size_t ws_size,
                              hipStream_t stream) {
  const float* x    = (const float*)d_in[0];
  const float* w_ih = (const float*)d_in[1];
  const float* w_hh = (const float*)d_in[2];
  const float* b_ih = (const float*)d_in[3];
  const float* b_hh = (const float*)d_in[4];
  float* out = (float*)d_out;

  char* ws = (char*)d_ws;
  f16*   fhi   = (f16*)(ws + 0);            // 1664*2144*2 = 7,135,232
  f16*   w16   = (f16*)(ws + 7135232);      // 2048*2144*2 = 8,785,920
  f16*   whh16 = (f16*)(ws + 15921152);     // 2048*512*2 = 2,097,152
  float* gx    = (float*)(ws + 18018304);   // 1664*2048*4 = 13,631,488
  unsigned short* hbuf  = (unsigned short*)(ws + 31649792); // 50 slots x 32KB = 1,638,400
  unsigned int*   ready = (unsigned int*)(ws + 33288192);   // 32 slots x 64B (512 u32)

  // bit-exact replication of np.linspace(1,600,51) + Python round (half-even)
  TV tv;
  double step = 599.0 / 50.0;
  for (int i = 0; i <= 50; i++) {
    double v = (double)i * step + 1.0;
    tv.v[i] = (int)nearbyint(v);
  }
  tv.v[50] = 600;

  unsigned int* gxcnt = ready + 512;        // 32 u32 tile counters

  prep_kernel<<<dim3(MP + CVB), dim3(256), 0, stream>>>(
      x, fhi, tv, (const float4*)w_ih, (const float4*)w_hh,
      (f16x4*)w16, (f16x4*)whh16, ready, b_ih, b_hh, (float4*)gx);

  fused_kernel<<<dim3(32 + WRK), dim3(256), 0, stream>>>(
      fhi, w16, b_ih, b_hh, whh16, gx, hbuf, ready, gxcnt, out);
}

// Round 11
// 239.139 us; speedup vs baseline: 1.0549x; 1.0549x over previous
//
#include <hip/hip_runtime.h>
#include <math.h>

typedef _Float16 f16;
typedef _Float16 f16x8 __attribute__((ext_vector_type(8)));
typedef _Float16 f16x4 __attribute__((ext_vector_type(4)));
typedef float    f32x4 __attribute__((ext_vector_type(4)));

#define BATCH 32
#define TT    600
#define CC    64
#define SEG   50
#define HH    512
#define G4    2048
#define FF    2144   // IN_SIZE = 64 + 2080
#define MM    1600   // BATCH*SEG
#define MP    1664   // padded: 52*32 (s-major) = 26*64 M-tiles
#define NPAIR 2016   // C*(C-1)/2
#define CVB   512    // convert blocks appended to prep grid
#define WRK   208    // gemm worker blocks (each does 8 of the 1664 K-split pieces)
#define SLOT16 16384 // u16 elements per h slot (32*512)
#define BUFB  12288  // ring buffer stride: A 4K + B 8K

struct TV { int v[51]; };

// async global->LDS, 16B per lane. LDS dest must be wave-uniform base + lane*16.
__device__ __forceinline__ void async_copy16(char* lds, const char* g) {
  __builtin_amdgcn_global_load_lds(
      (const __attribute__((address_space(1))) unsigned int*)g,
      (__attribute__((address_space(3))) unsigned int*)lds, 16, 0, 0);
}

__device__ __forceinline__ float sigm(float x) { return 1.f / (1.f + __expf(-x)); }
__device__ __forceinline__ float tanh_(float x) {
  float ax = fabsf(x);
  float e  = __expf(2.f * ax);
  float t  = 1.f - 2.f / (e + 1.f);   // robust for large |x|
  return x < 0.f ? -t : t;
}
__device__ __forceinline__ unsigned short f16_bits(f16 v) {
  union { f16 f; unsigned short u; } c; c.f = v; return c.u;
}

// ---------------- kernel 1: feats (blocks 0..MP-1) + weight convert / gx bias-init ----
// Plain cached stores; dispatch boundary makes them visible to the fused kernel.
__global__ void prep_kernel(const float* __restrict__ x, f16* __restrict__ fhi, TV tv,
                            const float4* __restrict__ w_ih, const float4* __restrict__ w_hh,
                            f16x4* __restrict__ w16, f16x4* __restrict__ whh16,
                            unsigned int* __restrict__ ready,
                            const float* __restrict__ bih, const float* __restrict__ bhh,
                            float4* __restrict__ gx4) {
  __shared__ float xs[13 * CC];
  int m   = blockIdx.x;
  int tid = threadIdx.x;

  if (m >= MP) {              // ---- convert role ----
    int cb   = m - MP;
    int gtid = cb * 256 + tid;
    int nth  = CVB * 256;
    for (int i = gtid; i < G4 * FF / 4; i += nth) {
      float4 v = w_ih[i];
      f16x4 o = {(f16)v.x, (f16)v.y, (f16)v.z, (f16)v.w};
      w16[i] = o;
    }
    for (int i = gtid; i < G4 * HH / 4; i += nth) {
      float4 v = w_hh[i];
      f16x4 o = {(f16)v.x, (f16)v.y, (f16)v.z, (f16)v.w};
      whh16[i] = o;
    }
    // gx bias-init: workers ATOMIC-ADD their K-piece partial sums on top, so the
    // bias (bih+bhh) is pre-seeded here instead of added in the GEMM epilogue.
    for (int i = gtid; i < MP * (G4 / 4); i += nth) {
      int c4 = i & (G4 / 4 - 1);
      float4 bi = ((const float4*)bih)[c4];
      float4 bh = ((const float4*)bhh)[c4];
      float4 o = {bi.x + bh.x, bi.y + bh.y, bi.z + bh.z, bi.w + bh.w};
      gx4[i] = o;
    }
    if (cb == 0)               // zero 32 ready slots (512 u32) + 32 gx tile counters
      for (int i = tid; i < 544; i += 256) ready[i] = 0u;
    return;
  }

  f16* rhi = fhi + (size_t)m * FF;
  if (m >= MM) {              // zero-pad rows 1600..1663 (s = 50,51) for the GEMM M-edge
    unsigned int* a = (unsigned int*)rhi;
    for (int i = tid; i < FF / 2; i += 256) a[i] = 0u;
    return;
  }
  int bb = m & 31, ss = m >> 5;
  int t0 = tv.v[ss] - 1, t1 = tv.v[ss + 1] - 1;
  int len = t1 - t0;          // #intervals in segment (11..12)
  for (int i = tid; i < (len + 1) * CC; i += 256)
    xs[i] = x[(size_t)bb * TT * CC + (size_t)(t0 + (i >> 6)) * CC + (i & 63)];
  __syncthreads();

  if (tid < CC) {             // inc (cols 0..63) and xa (cols 2080..2143)
    float xa  = xs[tid];
    float inc = xs[len * CC + tid] - xa;
    rhi[tid] = (f16)inc;
    rhi[2080 + tid] = (f16)xa;
  }

  int p0 = tid * 8;           // 252 threads x 8 pairs = 2016 upper-tri pairs
  if (p0 < NPAIR) {
    int c = 0, rem = p0;
    while (rem >= 63 - c) { rem -= 63 - c; c++; }
    int d = c + 1 + rem;
    int cs[8], dd[8];
#pragma unroll
    for (int i = 0; i < 8; i++) {
      cs[i] = c; dd[i] = d;
      d++; if (d == 64) { c++; d = c + 1; }
    }
    float acc[8], xc[8], xd[8];
#pragma unroll
    for (int i = 0; i < 8; i++) { acc[i] = 0.f; xc[i] = xs[cs[i]]; xd[i] = xs[dd[i]]; }
    for (int t = 1; t <= len; t++) {
#pragma unroll
      for (int i = 0; i < 8; i++) {      // Levy area: sum x_c*dx_d - x_d*dx_c
        float nc = xs[t * CC + cs[i]], nd = xs[t * CC + dd[i]];
        acc[i] += xc[i] * (nd - xd[i]) - xd[i] * (nc - xc[i]);
        xc[i] = nc; xd[i] = nd;
      }
    }
#pragma unroll
    for (int i = 0; i < 8; i++) {
      int ci = cs[i], di = dd[i];
      float xac = xs[ci], xad = xs[di];
      float incc = xs[len * CC + ci] - xac, incd = xs[len * CC + di] - xad;
      float v = 0.5f * acc[i] - 0.5f * (xac * incd - xad * incc);
      rhi[64 + p0 + i] = (f16)v;
    }
  }
}

// ---------------- kernel 2: fused GEMM + LSTM, regular launch (240 blocks co-resident) ----
// Blocks 0..31: persistent LSTM — round-3/7 proven skeleton BYTE-FOR-BYTE (plain tid0
//   gate poll, target 64). DMA->LDS slot consume is the proven-optimal form: zero VGPR
//   cost lets all 8 chunks fly concurrently, paying the L3 latency ONCE (direct-to-VGPR
//   refuted twice: r2 regalloc serialization, r10 insufficient pipeline depth).
// Blocks 32..239: GEMM workers, 4-WAY K-SPLIT: 1664 items (mt, kh in 0..3, nt), 8
//   rounds, mt-major ids — mt0 completes after a QUARTER-K piece spread over 64
//   round-0 workers. Partial sums f32-atomic-added into bias-seeded gx (validated r7).
//   Ring-5 counted-vmcnt pipeline (r3) + both-sides LDS swizzle (r5: conflicts
//   2.78M -> 102K). Counter target 64.
__global__ __launch_bounds__(256) void fused_kernel(
    const f16* __restrict__ fhi, const f16* __restrict__ w16,
    const float* __restrict__ bih, const float* __restrict__ bhh,
    const f16* __restrict__ whh16, float* __restrict__ gx,
    unsigned short* __restrict__ hbuf, unsigned int* __restrict__ ready,
    unsigned int* __restrict__ gxcnt, float* __restrict__ out) {
  __shared__ __align__(16) char smem[61440];  // gemm: 5 x 12KB ring ; lstm: hs 32K + gbuf 8K
  int tid  = threadIdx.x;
  int lane = tid & 63;

  if (blockIdx.x >= 32) {
    // ================= GEMM worker role =================
    int w  = blockIdx.x - 32;
    int wn = tid >> 6;
    int rowq = tid >> 2;            // 0..63 (LDS row this thread stages)
    int ldst = tid * 16;            // linear LDS dest (global_load_lds requirement)
    int quad = lane >> 4;           // 0..3 read quad
    int am   = lane & 15;

    // both-sides swizzle: LDS slot (row, q) holds global quad q ^ ((row>>1)&3).
    // The permutation is relative to the kt-chunk base (kbase-independent).
    int qsrc = ((tid & 3) ^ ((tid >> 3) & 3)) * 8;   // f16 elements within 32-col slice

    // precomputed swizzled read offsets (within one 12KB ring buffer)
    int offA[4], offB[2];
#pragma unroll
    for (int mi = 0; mi < 4; mi++) {
      int ra = mi * 16 + am;
      offA[mi] = ra * 64 + ((quad ^ ((ra >> 1) & 3)) * 16);
    }
#pragma unroll
    for (int ni = 0; ni < 2; ni++) {
      int rb = wn * 32 + ni * 16 + am;   // 0..127 spans B0 (pb0) then B1 (pb1)
      offB[ni] = 4096 + rb * 64 + ((quad ^ ((rb >> 1) & 3)) * 16);
    }

    for (int t = 0; t < 8; t++) {
      int id  = w + t * WRK;        // 0..1663
      int nt  = id & 15;
      int mtk = id >> 4;            // 0..103 (mt-major, kh inner)
      int kh  = mtk & 3;
      int mt  = mtk >> 2;           // 0..25
      int m0 = mt * 64, n0 = nt * 128;
      int kbase = kh * 544;         // f16 elements (17 iters x 32); kh3: 16 iters
      int KTh  = (kh == 3) ? 16 : 17;

      const f16* pa  = fhi + (size_t)(m0 + rowq) * FF + kbase + qsrc;
      const f16* pb0 = w16 + (size_t)(n0 + rowq) * FF + kbase + qsrc;
      const f16* pb1 = pb0 + (size_t)64 * FF;

      f32x4 zero4 = {0.f, 0.f, 0.f, 0.f};
      f32x4 acc[4][2];
#pragma unroll
      for (int i = 0; i < 4; i++) { acc[i][0] = zero4; acc[i][1] = zero4; }

      // prologue: stage kt = 0..2 into ring slots 0..2 (9 copies in flight)
      for (int kp = 0; kp < 3; kp++) {
        char* b = smem + kp * BUFB;
        int koff = kp * 32;
        async_copy16(b + ldst,        (const char*)(pa + koff));
        async_copy16(b + 4096 + ldst, (const char*)(pb0 + koff));
        async_copy16(b + 8192 + ldst, (const char*)(pb1 + koff));
      }

      for (int kt = 0; kt < KTh; kt++) {
        // prefetch kt+3 into ring slot (kt+3)%5; that slot was last READ at iter
        // kt-2 (completed before barrier kt-1) -> WAR is barrier-separated.
        if (kt + 3 < KTh) {
          char* b = smem + ((kt + 3) % 5) * BUFB;
          int koff = (kt + 3) * 32;
          async_copy16(b + ldst,        (const char*)(pa + koff));
          async_copy16(b + 4096 + ldst, (const char*)(pb0 + koff));
          async_copy16(b + 8192 + ldst, (const char*)(pb1 + koff));
          asm volatile("s_waitcnt vmcnt(9)" ::: "memory");   // kt's 3 copies done
        } else if (kt + 3 == KTh) {
          asm volatile("s_waitcnt vmcnt(6)" ::: "memory");
        } else if (kt + 2 == KTh) {
          asm volatile("s_waitcnt vmcnt(3)" ::: "memory");
        } else {
          asm volatile("s_waitcnt vmcnt(0)" ::: "memory");
        }
        __builtin_amdgcn_s_barrier();       // all waves' kt-copies complete
        __builtin_amdgcn_sched_barrier(0);  // no ds_read hoist above the barrier

        char* bb = smem + (kt % 5) * BUFB;
        f16x8 bfr[2];
        bfr[0] = *(const f16x8*)(bb + offB[0]);
        bfr[1] = *(const f16x8*)(bb + offB[1]);
#pragma unroll
        for (int mi = 0; mi < 4; mi++) {
          f16x8 ah = *(const f16x8*)(bb + offA[mi]);
#pragma unroll
          for (int ni = 0; ni < 2; ni++)
            acc[mi][ni] = __builtin_amdgcn_mfma_f32_16x16x32_f16(ah, bfr[ni], acc[mi][ni], 0, 0, 0);
        }
      }

      // epilogue: f32 atomic-add partial sums into bias-seeded gx. Atomics act at
      // L3 (device coherence point); __syncthreads drains vmcnt(0) so all adds are
      // globally visible before the tile counter increments.
#pragma unroll
      for (int ni = 0; ni < 2; ni++) {
        int ncol = n0 + wn * 32 + ni * 16 + am;
#pragma unroll
        for (int mi = 0; mi < 4; mi++) {
          int mrow = m0 + mi * 16 + quad * 4;
#pragma unroll
          for (int r = 0; r < 4; r++)
            __hip_atomic_fetch_add(&gx[(size_t)(mrow + r) * G4 + ncol],
                                   acc[mi][ni][r],
                                   __ATOMIC_RELAXED, __HIP_MEMORY_SCOPE_AGENT);
        }
      }
      __syncthreads();   // drains vmcnt(0): all this block's gx adds acked
      if (tid == 0)
        __hip_atomic_fetch_add(&gxcnt[mt], 1u, __ATOMIC_RELAXED,
                               __HIP_MEMORY_SCOPE_AGENT);
    }
    return;
  }

  // ================= LSTM role (blocks 0..31) — round-3/7 proven structure =================
  f16* hs = (f16*)smem;                         // 32 KB, layout [k8][b][8] fp16
  float* gb = (float*)(smem + 32768);           // 8 KB gate exchange [gate][b][16]

  int gate = tid >> 6;
  int u0   = blockIdx.x * 16;
  int wg   = blockIdx.x;

  // preload w_hh fragments: B[k][n] = w_hh[n][k], n = gate*512 + u0 + (lane&15)
  f16x8 bf[16];
  {
    const f16* wrow = whh16 + (size_t)(gate * HH + u0 + (lane & 15)) * HH + (lane >> 4) * 8;
#pragma unroll
    for (int ks = 0; ks < 16; ks++) bf[ks] = *(const f16x8*)(wrow + ks * 32);
  }

  int b1 = tid >> 4;
  int ul = tid & 15;
  float cst0 = 0.f, cst1 = 0.f;
  int aq  = (lane >> 4);
  int am  = (lane & 15);
  int col = lane & 15;
  int rbase = (lane >> 4) * 4;

  for (int s = 0; s < SEG; s++) {
    // gate on gx M-tile (s>>1); odd s was confirmed at s-1. The __syncthreads after
    // the poll orders the subsequent plain gx loads (no hoist past a barrier).
    if ((s & 1) == 0) {
      if (tid == 0) {
        while (__hip_atomic_load(&gxcnt[s >> 1], __ATOMIC_RELAXED,
                                 __HIP_MEMORY_SCOPE_AGENT) < 64u)
          __builtin_amdgcn_s_sleep(1);
      }
      __syncthreads();
    }

    // gx prefetch (plain cached loads; post-gate first touch -> fresh from L3)
    float gxr0[4], gxr1[4];
#pragma unroll
    for (int r = 0; r < 4; r++) {
      int b = rbase + r;
      gxr0[r] = gx[(size_t)((s << 5) + b) * G4 + gate * HH + u0 + col];
      gxr1[r] = gx[(size_t)((s << 5) + b + 16) * G4 + gate * HH + u0 + col];
    }

    f32x4 acc0 = {0.f, 0.f, 0.f, 0.f};
    f32x4 acc1 = {0.f, 0.f, 0.f, 0.f};

    if (s > 0) {
      // wait: all 32 WGs published h[s]
      unsigned int tgt = (unsigned int)s;
      if (tid < 32) {
        while (__hip_atomic_load(&ready[tid * 16], __ATOMIC_RELAXED,
                                 __HIP_MEMORY_SCOPE_AGENT) < tgt)
          __builtin_amdgcn_s_sleep(1);
      }
      __syncthreads();

      // stage h[s] slot -> LDS via async DMA: 8 x 16B/thread, all in flight,
      // one drain at the barrier (no VGPR round-trip, no serialized batches)
      const char* hrd = (const char*)(hbuf + (size_t)s * SLOT16);
#pragma unroll
      for (int c = 0; c < 8; c++)
        async_copy16((char*)hs + c * 4096 + tid * 16, hrd + c * 4096 + tid * 16);
      __syncthreads();

#pragma unroll
      for (int ks = 0; ks < 16; ks++) {
        f16x8 a0 = *(const f16x8*)((char*)hs + (((ks * 4 + aq) * 32) + am) * 16);
        f16x8 a1 = *(const f16x8*)((char*)hs + (((ks * 4 + aq) * 32) + 16 + am) * 16);
        acc0 = __builtin_amdgcn_mfma_f32_16x16x32_f16(a0, bf[ks], acc0, 0, 0, 0);
        acc1 = __builtin_amdgcn_mfma_f32_16x16x32_f16(a1, bf[ks], acc1, 0, 0, 0);
      }
    }

#pragma unroll
    for (int r = 0; r < 4; r++) {
      int b = rbase + r;
      gb[(gate * 32 + b) * 16 + col]      = acc0[r] + gxr0[r];
      gb[(gate * 32 + b + 16) * 16 + col] = acc1[r] + gxr1[r];
    }
    __syncthreads();

    unsigned short* hwr = hbuf + (size_t)(s + 1) * SLOT16;
    int k = u0 + ul;
    float h0, h1;
    {
      float i_ = sigm(gb[(0 * 32 + b1) * 16 + ul]), f_ = sigm(gb[(1 * 32 + b1) * 16 + ul]);
      float g_ = tanh_(gb[(2 * 32 + b1) * 16 + ul]), o_ = sigm(gb[(3 * 32 + b1) * 16 + ul]);
      cst0 = f_ * cst0 + i_ * g_;
      h0 = o_ * tanh_(cst0);
    }
    {
      int b2 = b1 + 16;
      float i_ = sigm(gb[(0 * 32 + b2) * 16 + ul]), f_ = sigm(gb[(1 * 32 + b2) * 16 + ul]);
      float g_ = tanh_(gb[(2 * 32 + b2) * 16 + ul]), o_ = sigm(gb[(3 * 32 + b2) * 16 + ul]);
      cst1 = f_ * cst1 + i_ * g_;
      h1 = o_ * tanh_(cst1);
    }

    if (s < SEG - 1) {
      // publish h[s+1] into slot s+1 (sc1, write-through); __syncthreads drains
      // vmcnt(0) so stores are at the coherence point before the flag goes out
      __hip_atomic_store(hwr + ((k >> 3) * 32 + b1) * 8 + (k & 7),
                         f16_bits((f16)h0), __ATOMIC_RELAXED, __HIP_MEMORY_SCOPE_AGENT);
      __hip_atomic_store(hwr + ((k >> 3) * 32 + (b1 + 16)) * 8 + (k & 7),
                         f16_bits((f16)h1), __ATOMIC_RELAXED, __HIP_MEMORY_SCOPE_AGENT);
      __syncthreads();
      if (tid == 0)
        __hip_atomic_store(&ready[wg * 16], (unsigned int)(s + 1),
                           __ATOMIC_RELAXED, __HIP_MEMORY_SCOPE_AGENT);
    }

    // out stores AFTER the flag publish: their HBM ack is off the critical chain
    out[(size_t)(b1 * SEG + s) * HH + k] = h0;
    out[(size_t)((b1 + 16) * SEG + s) * HH + k] = h1;
  }
}

// ---------------- launch ----------------
extern "C" void kernel_launch(void* const* d_in, const int* in_sizes, int n_in,
                              void* d_out, int out_size, void* d_ws, size_t ws_size,
                              hipStream_t stream) {
  const float* x    = (const float*)d_in[0];
  const float* w_ih = (const float*)d_in[1];
  const float* w_hh = (const float*)d_in[2];
  const float* b_ih = (const float*)d_in[3];
  const float* b_hh = (const float*)d_in[4];
  float* out = (float*)d_out;

  char* ws = (char*)d_ws;
  f16*   fhi   = (f16*)(ws + 0);            // 1664*2144*2 = 7,135,232
  f16*   w16   = (f16*)(ws + 7135232);      // 2048*2144*2 = 8,785,920
  f16*   whh16 = (f16*)(ws + 15921152);     // 2048*512*2 = 2,097,152
  float* gx    = (float*)(ws + 18018304);   // 1664*2048*4 = 13,631,488
  unsigned short* hbuf  = (unsigned short*)(ws + 31649792); // 50 slots x 32KB = 1,638,400
  unsigned int*   ready = (unsigned int*)(ws + 33288192);   // 32 slots x 64B (512 u32)

  // bit-exact replication of np.linspace(1,600,51) + Python round (half-even)
  TV tv;
  double step = 599.0 / 50.0;
  for (int i = 0; i <= 50; i++) {
    double v = (double)i * step + 1.0;
    tv.v[i] = (int)nearbyint(v);
  }
  tv.v[50] = 600;

  unsigned int* gxcnt = ready + 512;        // 32 u32 tile counters

  prep_kernel<<<dim3(MP + CVB), dim3(256), 0, stream>>>(
      x, fhi, tv, (const float4*)w_ih, (const float4*)w_hh,
      (f16x4*)w16, (f16x4*)whh16, ready, b_ih, b_hh, (float4*)gx);

  fused_kernel<<<dim3(32 + WRK), dim3(256), 0, stream>>>(
      fhi, w16, b_ih, b_hh, whh16, gx, hbuf, ready, gxcnt, out);
}